// Round 2
// baseline (290.943 us; speedup 1.0000x reference)
//
#include <hip/hip_runtime.h>

#define LOG2E 1.4426950408889634f
#define SCALE 0.17677669529663687f  // 1/sqrt(32)
#define NEGBIG -1e10f

typedef __attribute__((ext_vector_type(8))) short bfrag;   // 8 bf16
typedef __attribute__((ext_vector_type(4))) float ffrag;   // 4 f32 acc
typedef __attribute__((ext_vector_type(8))) float f8v;

__device__ __forceinline__ short f2bf(float x) {
  union { float f; unsigned u; } v; v.f = x;
  return (short)((v.u + 0x7fffu + ((v.u >> 16) & 1u)) >> 16);  // RNE
}

__device__ __forceinline__ bfrag cvt8(const float* __restrict__ p) {
  f8v x = *(const f8v*)p;
  bfrag r;
#pragma unroll
  for (int i = 0; i < 8; ++i) r[i] = f2bf(x[i]);
  return r;
}

// ---- K projection: K[r][d] = sum_f key[r][f]*Wk[d][f] + bk[d], bf16 [16384][256]
// grid (256, 2): x = m-tile(64 rows), y = n-tile(128 d). Weights converted in-flight.
__global__ __launch_bounds__(256) void proj_k(
    const float* __restrict__ kin, const float* __restrict__ Wk,
    const float* __restrict__ bk, short* __restrict__ ko) {
  const int lane = threadIdx.x & 63, wid = threadIdx.x >> 6;
  const int lrow = lane & 15, lq = lane >> 4;
  const int wm = wid >> 1, wn = wid & 1;
  const int m0 = blockIdx.x * 64 + wm * 32;
  const int n0 = blockIdx.y * 128 + wn * 64;
  ffrag acc[2][4] = {};
#pragma unroll
  for (int k0 = 0; k0 < 256; k0 += 32) {
    bfrag a[2], b[4];
#pragma unroll
    for (int i = 0; i < 2; ++i)
      a[i] = cvt8(kin + (size_t)(m0 + i * 16 + lrow) * 256 + k0 + lq * 8);
#pragma unroll
    for (int j = 0; j < 4; ++j)
      b[j] = cvt8(Wk + (size_t)(n0 + j * 16 + lrow) * 256 + k0 + lq * 8);
#pragma unroll
    for (int i = 0; i < 2; ++i)
#pragma unroll
      for (int j = 0; j < 4; ++j)
        acc[i][j] = __builtin_amdgcn_mfma_f32_16x16x32_bf16(a[i], b[j], acc[i][j], 0, 0, 0);
  }
#pragma unroll
  for (int j = 0; j < 4; ++j) {
    int d = n0 + j * 16 + lrow;
    float bs = bk[d];
#pragma unroll
    for (int i = 0; i < 2; ++i)
#pragma unroll
      for (int r = 0; r < 4; ++r) {
        int row = m0 + i * 16 + lq * 4 + r;
        ko[(size_t)row * 256 + d] = f2bf(acc[i][j][r] + bs);
      }
  }
}

// ---- V projection, transposed out: Vt[bt][d][s], bf16 ----
// grid (128, 4): x = row-tile(128), y = d-tile(64). Weights converted in-flight.
__global__ __launch_bounds__(256) void proj_v(
    const float* __restrict__ vin, const float* __restrict__ Wv,
    const float* __restrict__ bv, short* __restrict__ vt) {
  const int lane = threadIdx.x & 63, wid = threadIdx.x >> 6;
  const int lrow = lane & 15, lq = lane >> 4;
  const int wm = wid >> 1, wn = wid & 1;
  const int m0 = blockIdx.y * 64 + wm * 32;    // d
  const int n0 = blockIdx.x * 128 + wn * 64;   // row
  ffrag acc[2][4] = {};
#pragma unroll
  for (int k0 = 0; k0 < 256; k0 += 32) {
    bfrag a[2], b[4];
#pragma unroll
    for (int i = 0; i < 2; ++i)
      a[i] = cvt8(Wv + (size_t)(m0 + i * 16 + lrow) * 256 + k0 + lq * 8);
#pragma unroll
    for (int j = 0; j < 4; ++j)
      b[j] = cvt8(vin + (size_t)(n0 + j * 16 + lrow) * 256 + k0 + lq * 8);
#pragma unroll
    for (int i = 0; i < 2; ++i)
#pragma unroll
      for (int j = 0; j < 4; ++j)
        acc[i][j] = __builtin_amdgcn_mfma_f32_16x16x32_bf16(a[i], b[j], acc[i][j], 0, 0, 0);
  }
#pragma unroll
  for (int i = 0; i < 2; ++i)
#pragma unroll
    for (int r = 0; r < 4; ++r) {
      int d = m0 + i * 16 + lq * 4 + r;
      float bs = bv[d];
#pragma unroll
      for (int j = 0; j < 4; ++j) {
        int row = n0 + j * 16 + lrow;
        int bt = row >> 10, sl = row & 1023;
        vt[(size_t)bt * 262144 + (size_t)d * 1024 + sl] = f2bf(acc[i][j][r] + bs);
      }
    }
}

// ---- fused: Q-proj -> flash attention (all 8 heads) -> out-proj ----
// grid (32, 16): x = q-tile(32 rows), y = bt. 4 waves; each wave owns 2 heads.
__global__ __launch_bounds__(256) void attn_fused(
    const float* __restrict__ query, const float* __restrict__ Wq,
    const float* __restrict__ bq, const float* __restrict__ Wo,
    const float* __restrict__ bo, const short* __restrict__ K,
    const short* __restrict__ Vt, const int* __restrict__ mask,
    float* __restrict__ out) {
  const int lane = threadIdx.x & 63, wid = threadIdx.x >> 6;
  const int lrow = lane & 15, lq = lane >> 4;
  const int bt = blockIdx.y;
  const int q0 = blockIdx.x * 32;
  const int L = mask[bt];

  // Q tile (later reused in-place as X tile): [32][256], stride 264 (row = 528B, 16B-aligned)
  __shared__ __align__(16) short qx[32 * 264];
  // per-wave P tile [32][64], stride 72
  __shared__ __align__(16) short pbuf[4][32 * 72];
  short* P = pbuf[wid];

  // ---- phase 1: Q projection into LDS; wave computes cols wid*64..+63 ----
  {
    const int n0 = wid * 64;
    const float* X = query + ((size_t)bt * 1024 + q0) * 256;
    ffrag acc[2][4] = {};
#pragma unroll
    for (int k0 = 0; k0 < 256; k0 += 32) {
      bfrag a[2], b[4];
#pragma unroll
      for (int i = 0; i < 2; ++i)
        a[i] = cvt8(X + (size_t)(i * 16 + lrow) * 256 + k0 + lq * 8);
#pragma unroll
      for (int j = 0; j < 4; ++j)
        b[j] = cvt8(Wq + (size_t)(n0 + j * 16 + lrow) * 256 + k0 + lq * 8);
#pragma unroll
      for (int i = 0; i < 2; ++i)
#pragma unroll
        for (int j = 0; j < 4; ++j)
          acc[i][j] = __builtin_amdgcn_mfma_f32_16x16x32_bf16(a[i], b[j], acc[i][j], 0, 0, 0);
    }
#pragma unroll
    for (int j = 0; j < 4; ++j) {
      int d = n0 + j * 16 + lrow;
      float bs = bq[d];
#pragma unroll
      for (int i = 0; i < 2; ++i)
#pragma unroll
        for (int r = 0; r < 4; ++r)
          qx[(i * 16 + lq * 4 + r) * 264 + d] = f2bf(acc[i][j][r] + bs);
    }
  }
  __syncthreads();

  // ---- phase 2: flash attention; wave processes heads wid*2 and wid*2+1 ----
  const short* Kb = K + (size_t)bt * 262144;  // [1024][256]
#pragma unroll 1
  for (int hh = 0; hh < 2; ++hh) {
    const int h = wid * 2 + hh;
    const short* Vb = Vt + ((size_t)bt * 8 + h) * 32768;  // [32][1024]
    bfrag qf[2];
#pragma unroll
    for (int i = 0; i < 2; ++i)
      qf[i] = *(const bfrag*)(qx + (i * 16 + lrow) * 264 + h * 32 + lq * 8);
    float m_i[2][4], l_i[2][4];
    ffrag o[2][2] = {};
#pragma unroll
    for (int i = 0; i < 2; ++i)
#pragma unroll
      for (int r = 0; r < 4; ++r) { m_i[i][r] = -INFINITY; l_i[i][r] = 0.f; }

    for (int kc = 0; kc < 1024; kc += 64) {
      ffrag s[2][4];
      const ffrag zf = {0.f, 0.f, 0.f, 0.f};
#pragma unroll
      for (int f = 0; f < 4; ++f) {
        bfrag kf = *(const bfrag*)(Kb + (size_t)(kc + f * 16 + lrow) * 256 + h * 32 + lq * 8);
#pragma unroll
        for (int i = 0; i < 2; ++i)
          s[i][f] = __builtin_amdgcn_mfma_f32_16x16x32_bf16(qf[i], kf, zf, 0, 0, 0);
      }
      // mask + scale (either index >= L -> NEG; fully-masked rows fall out uniform like ref)
#pragma unroll
      for (int f = 0; f < 4; ++f) {
        int kr = kc + f * 16 + lrow;
#pragma unroll
        for (int i = 0; i < 2; ++i)
#pragma unroll
          for (int r = 0; r < 4; ++r) {
            int qr = q0 + i * 16 + lq * 4 + r;
            bool valid = (kr < L) && (qr < L);
            s[i][f][r] = valid ? s[i][f][r] * SCALE : NEGBIG;
          }
      }
      float alpha[2][4];
#pragma unroll
      for (int i = 0; i < 2; ++i)
#pragma unroll
        for (int r = 0; r < 4; ++r) {
          float mx = fmaxf(fmaxf(s[i][0][r], s[i][1][r]), fmaxf(s[i][2][r], s[i][3][r]));
          mx = fmaxf(mx, __shfl_xor(mx, 1));
          mx = fmaxf(mx, __shfl_xor(mx, 2));
          mx = fmaxf(mx, __shfl_xor(mx, 4));
          mx = fmaxf(mx, __shfl_xor(mx, 8));
          float mnew = fmaxf(m_i[i][r], mx);
          alpha[i][r] = exp2f((m_i[i][r] - mnew) * LOG2E);
          m_i[i][r] = mnew;
          float rs = 0.f;
#pragma unroll
          for (int f = 0; f < 4; ++f) {
            float p = exp2f((s[i][f][r] - mnew) * LOG2E);
            s[i][f][r] = p;
            rs += p;
          }
          rs += __shfl_xor(rs, 1);
          rs += __shfl_xor(rs, 2);
          rs += __shfl_xor(rs, 4);
          rs += __shfl_xor(rs, 8);
          l_i[i][r] = l_i[i][r] * alpha[i][r] + rs;
        }
      // P -> per-wave LDS (same-wave DS ops are in-order)
#pragma unroll
      for (int i = 0; i < 2; ++i)
#pragma unroll
        for (int f = 0; f < 4; ++f)
#pragma unroll
          for (int r = 0; r < 4; ++r)
            P[(i * 16 + lq * 4 + r) * 72 + f * 16 + lrow] = f2bf(s[i][f][r]);
#pragma unroll
      for (int i = 0; i < 2; ++i)
#pragma unroll
        for (int j = 0; j < 2; ++j)
#pragma unroll
          for (int r = 0; r < 4; ++r) o[i][j][r] *= alpha[i][r];
#pragma unroll
      for (int i = 0; i < 2; ++i) {
        bfrag a0 = *(const bfrag*)(P + (i * 16 + lrow) * 72 + lq * 8);
        bfrag a1 = *(const bfrag*)(P + (i * 16 + lrow) * 72 + 32 + lq * 8);
#pragma unroll
        for (int j = 0; j < 2; ++j) {
          bfrag v0 = *(const bfrag*)(Vb + (size_t)(j * 16 + lrow) * 1024 + kc + lq * 8);
          bfrag v1 = *(const bfrag*)(Vb + (size_t)(j * 16 + lrow) * 1024 + kc + 32 + lq * 8);
          o[i][j] = __builtin_amdgcn_mfma_f32_16x16x32_bf16(a0, v0, o[i][j], 0, 0, 0);
          o[i][j] = __builtin_amdgcn_mfma_f32_16x16x32_bf16(a1, v1, o[i][j], 0, 0, 0);
        }
      }
    }
    // write x in place over this head's Q columns (only this wave touches cols h*32..+31)
#pragma unroll
    for (int i = 0; i < 2; ++i)
#pragma unroll
      for (int j = 0; j < 2; ++j)
#pragma unroll
        for (int r = 0; r < 4; ++r)
          qx[(i * 16 + lq * 4 + r) * 264 + h * 32 + j * 16 + lrow] =
              f2bf(o[i][j][r] / l_i[i][r]);
  }
  __syncthreads();

  // ---- phase 3: output projection; wave computes cols wid*64..+63 ----
  {
    const int n0 = wid * 64;
    ffrag acc[2][4] = {};
#pragma unroll
    for (int k0 = 0; k0 < 256; k0 += 32) {
      bfrag a[2], b[4];
#pragma unroll
      for (int i = 0; i < 2; ++i)
        a[i] = *(const bfrag*)(qx + (i * 16 + lrow) * 264 + k0 + lq * 8);
#pragma unroll
      for (int j = 0; j < 4; ++j)
        b[j] = cvt8(Wo + (size_t)(n0 + j * 16 + lrow) * 256 + k0 + lq * 8);
#pragma unroll
      for (int i = 0; i < 2; ++i)
#pragma unroll
        for (int j = 0; j < 4; ++j)
          acc[i][j] = __builtin_amdgcn_mfma_f32_16x16x32_bf16(a[i], b[j], acc[i][j], 0, 0, 0);
    }
#pragma unroll
    for (int j = 0; j < 4; ++j) {
      int d = n0 + j * 16 + lrow;
      float bs = bo[d];
#pragma unroll
      for (int i = 0; i < 2; ++i)
#pragma unroll
        for (int r = 0; r < 4; ++r)
          out[((size_t)bt * 1024 + q0 + i * 16 + lq * 4 + r) * 256 + d] =
              acc[i][j][r] + bs;
    }
  }
}

extern "C" void kernel_launch(void* const* d_in, const int* in_sizes, int n_in,
                              void* d_out, int out_size, void* d_ws, size_t ws_size,
                              hipStream_t stream) {
  const float* query = (const float*)d_in[0];
  const float* key   = (const float*)d_in[1];
  const float* value = (const float*)d_in[2];
  const int*   mask  = (const int*)d_in[3];
  const float* Wq = (const float*)d_in[4];
  const float* bq = (const float*)d_in[5];
  const float* Wk = (const float*)d_in[6];
  const float* bk = (const float*)d_in[7];
  const float* Wv = (const float*)d_in[8];
  const float* bv = (const float*)d_in[9];
  const float* Wo = (const float*)d_in[10];
  const float* bo = (const float*)d_in[11];
  float* out = (float*)d_out;

  // workspace: K bf16 (8 MB) + Vt bf16 (8 MB) = 16,777,216 bytes exactly
  short* k_ws  = (short*)d_ws;
  short* vt_ws = k_ws + 4194304;

  proj_k<<<dim3(256, 2), 256, 0, stream>>>(key, Wk, bk, k_ws);
  proj_v<<<dim3(128, 4), 256, 0, stream>>>(value, Wv, bv, vt_ws);
  attn_fused<<<dim3(32, 16), 256, 0, stream>>>(query, Wq, bq, Wo, bo,
                                               k_ws, vt_ws, mask, out);
}

// Round 3
// 277.391 us; speedup vs baseline: 1.0489x; 1.0489x over previous
//
#include <hip/hip_runtime.h>

#define LOG2E 1.4426950408889634f
#define SCALE 0.17677669529663687f  // 1/sqrt(32)
#define NEGBIG -1e10f

typedef __attribute__((ext_vector_type(8))) short bfrag;   // 8 bf16
typedef __attribute__((ext_vector_type(4))) float ffrag;   // 4 f32 acc
typedef __attribute__((ext_vector_type(8))) unsigned int u8v;
typedef __attribute__((ext_vector_type(4))) unsigned int u4v;

__device__ __forceinline__ short f2bf(float x) {
  union { float f; unsigned u; } v; v.f = x;
  return (short)((v.u + 0x8000u) >> 16);  // round-half-up (==RNE except exact ties)
}

// 8 fp32 -> 8 bf16 via v_perm_b32 packing (3 VALU per 2 elements)
__device__ __forceinline__ bfrag cvt8(const float* __restrict__ p) {
  u8v x = *(const u8v*)p;
  u4v r;
#pragma unroll
  for (int i = 0; i < 4; ++i)
    r[i] = __builtin_amdgcn_perm(x[2 * i + 1] + 0x8000u, x[2 * i] + 0x8000u, 0x07060302u);
  union { u4v u; bfrag b; } c; c.u = r; return c.b;
}

// ---- K projection: K[r][d] = sum_f key[r][f]*Wk[d][f] + bk[d], bf16 [16384][256]
// grid (256, 2): x = m-tile(64 rows), y = n-tile(128 d)
__global__ __launch_bounds__(256) void proj_k(
    const float* __restrict__ kin, const float* __restrict__ Wk,
    const float* __restrict__ bk, short* __restrict__ ko) {
  const int lane = threadIdx.x & 63, wid = threadIdx.x >> 6;
  const int lrow = lane & 15, lq = lane >> 4;
  const int wm = wid >> 1, wn = wid & 1;
  const int m0 = blockIdx.x * 64 + wm * 32;
  const int n0 = blockIdx.y * 128 + wn * 64;
  __shared__ __align__(16) short tile[64 * 136];
  ffrag acc[2][4] = {};
#pragma unroll
  for (int k0 = 0; k0 < 256; k0 += 32) {
    bfrag a[2], b[4];
#pragma unroll
    for (int i = 0; i < 2; ++i)
      a[i] = cvt8(kin + (size_t)(m0 + i * 16 + lrow) * 256 + k0 + lq * 8);
#pragma unroll
    for (int j = 0; j < 4; ++j)
      b[j] = cvt8(Wk + (size_t)(n0 + j * 16 + lrow) * 256 + k0 + lq * 8);
#pragma unroll
    for (int i = 0; i < 2; ++i)
#pragma unroll
      for (int j = 0; j < 4; ++j)
        acc[i][j] = __builtin_amdgcn_mfma_f32_16x16x32_bf16(a[i], b[j], acc[i][j], 0, 0, 0);
  }
#pragma unroll
  for (int j = 0; j < 4; ++j) {
    int dl = wn * 64 + j * 16 + lrow;
    float bs = bk[blockIdx.y * 128 + dl];
#pragma unroll
    for (int i = 0; i < 2; ++i)
#pragma unroll
      for (int r = 0; r < 4; ++r)
        tile[(wm * 32 + i * 16 + lq * 4 + r) * 136 + dl] = f2bf(acc[i][j][r] + bs);
  }
  __syncthreads();
#pragma unroll
  for (int s = 0; s < 4; ++s) {
    int id = s * 256 + threadIdx.x;
    int row = id >> 4, c = id & 15;
    bfrag v = *(const bfrag*)(tile + row * 136 + c * 8);
    *(bfrag*)(ko + (size_t)(blockIdx.x * 64 + row) * 256 + blockIdx.y * 128 + c * 8) = v;
  }
}

// ---- V projection, transposed out: Vt[bt][d][s], bf16 ----
// grid (128, 4): x = row-tile(128), y = d-tile(64)
__global__ __launch_bounds__(256) void proj_v(
    const float* __restrict__ vin, const float* __restrict__ Wv,
    const float* __restrict__ bv, short* __restrict__ vt) {
  const int lane = threadIdx.x & 63, wid = threadIdx.x >> 6;
  const int lrow = lane & 15, lq = lane >> 4;
  const int wm = wid >> 1, wn = wid & 1;
  const int m0 = blockIdx.y * 64 + wm * 32;    // d
  const int n0 = blockIdx.x * 128 + wn * 64;   // row
  __shared__ __align__(16) short tile[64 * 136];
  ffrag acc[2][4] = {};
#pragma unroll
  for (int k0 = 0; k0 < 256; k0 += 32) {
    bfrag a[2], b[4];
#pragma unroll
    for (int i = 0; i < 2; ++i)
      a[i] = cvt8(Wv + (size_t)(m0 + i * 16 + lrow) * 256 + k0 + lq * 8);
#pragma unroll
    for (int j = 0; j < 4; ++j)
      b[j] = cvt8(vin + (size_t)(n0 + j * 16 + lrow) * 256 + k0 + lq * 8);
#pragma unroll
    for (int i = 0; i < 2; ++i)
#pragma unroll
      for (int j = 0; j < 4; ++j)
        acc[i][j] = __builtin_amdgcn_mfma_f32_16x16x32_bf16(a[i], b[j], acc[i][j], 0, 0, 0);
  }
#pragma unroll
  for (int i = 0; i < 2; ++i)
#pragma unroll
    for (int r = 0; r < 4; ++r) {
      int dl = wm * 32 + i * 16 + lq * 4 + r;
      float bs = bv[blockIdx.y * 64 + dl];
#pragma unroll
      for (int j = 0; j < 4; ++j)
        tile[dl * 136 + wn * 64 + j * 16 + lrow] = f2bf(acc[i][j][r] + bs);
    }
  __syncthreads();
  const int bt = blockIdx.x >> 3;
  const int sl0 = (blockIdx.x & 7) * 128;
#pragma unroll
  for (int s = 0; s < 4; ++s) {
    int id = s * 256 + threadIdx.x;
    int row = id >> 4, c = id & 15;
    bfrag v = *(const bfrag*)(tile + row * 136 + c * 8);
    *(bfrag*)(vt + (size_t)bt * 262144 + (size_t)(blockIdx.y * 64 + row) * 1024 + sl0 + c * 8) = v;
  }
}

// ---- fused: Q-proj -> flash attention (1 head/wave, 8 waves) -> out-proj ----
// 1-D grid of 512 blocks, swizzled so same-bt blocks cluster per XCD (id%8).
__global__ __launch_bounds__(512, 4) void attn_fused(
    const float* __restrict__ query, const float* __restrict__ Wq,
    const float* __restrict__ bq, const float* __restrict__ Wo,
    const float* __restrict__ bo, const short* __restrict__ K,
    const short* __restrict__ Vt, const int* __restrict__ mask,
    float* __restrict__ out) {
  const int lane = threadIdx.x & 63, wid = threadIdx.x >> 6;  // wid 0..7
  const int lrow = lane & 15, lq = lane >> 4;
  const int id = blockIdx.x;
  const int bt = ((id & 7) << 1) + ((id >> 3) & 1);   // cluster 2 bt per XCD (if xcd==id%8)
  const int q0 = (id >> 4) * 32;
  const int L = mask[bt];

  // Q tile, reused in-place as X tile: [32][256], stride 264 (528B rows: 16B-aligned, 2-way banks)
  __shared__ __align__(16) short qx[32 * 264];
  // per-wave P tile [32 rows][64 cols], stride 72
  __shared__ __align__(16) short pbuf[8][32 * 72];
  short* P = pbuf[wid];

  // ---- phase 1: Q projection into LDS; wave computes its own head's cols wid*32..+31 ----
  {
    const int n0 = wid * 32;
    const float* X = query + ((size_t)bt * 1024 + q0) * 256;
    ffrag acc[2][2] = {};
#pragma unroll
    for (int k0 = 0; k0 < 256; k0 += 32) {
      bfrag a[2], b[2];
#pragma unroll
      for (int i = 0; i < 2; ++i)
        a[i] = cvt8(X + (size_t)(i * 16 + lrow) * 256 + k0 + lq * 8);
#pragma unroll
      for (int j = 0; j < 2; ++j)
        b[j] = cvt8(Wq + (size_t)(n0 + j * 16 + lrow) * 256 + k0 + lq * 8);
#pragma unroll
      for (int i = 0; i < 2; ++i)
#pragma unroll
        for (int j = 0; j < 2; ++j)
          acc[i][j] = __builtin_amdgcn_mfma_f32_16x16x32_bf16(a[i], b[j], acc[i][j], 0, 0, 0);
    }
#pragma unroll
    for (int j = 0; j < 2; ++j) {
      int d = n0 + j * 16 + lrow;
      float bs = bq[d];
#pragma unroll
      for (int i = 0; i < 2; ++i)
#pragma unroll
        for (int r = 0; r < 4; ++r)
          qx[(i * 16 + lq * 4 + r) * 264 + d] = f2bf(acc[i][j][r] + bs);
    }
  }
  // no barrier: each wave reads only its own columns until phase 3

  // ---- phase 2: flash attention, head h = wid ----
  const int h = wid;
  const short* Kb = K + (size_t)bt * 262144;                // [1024][256]
  const short* Vb = Vt + ((size_t)bt * 8 + h) * 32768;      // [32][1024]
  bfrag qf[2];
#pragma unroll
  for (int i = 0; i < 2; ++i)
    qf[i] = *(const bfrag*)(qx + (i * 16 + lrow) * 264 + h * 32 + lq * 8);

  const int nvalid = min(max(L - q0, 0), 32);
  const int nchunk = (nvalid > 0) ? ((L + 63) >> 6) : 0;

  float m_i[2][4], l_i[2][4];
  ffrag o[2][2] = {};
#pragma unroll
  for (int i = 0; i < 2; ++i)
#pragma unroll
    for (int r = 0; r < 4; ++r) { m_i[i][r] = -INFINITY; l_i[i][r] = 0.f; }

  for (int c = 0; c < nchunk; ++c) {
    const int kc = c * 64;
    ffrag s[2][4];
    const ffrag zf = {0.f, 0.f, 0.f, 0.f};
#pragma unroll
    for (int f = 0; f < 4; ++f) {
      bfrag kf = *(const bfrag*)(Kb + (size_t)(kc + f * 16 + lrow) * 256 + h * 32 + lq * 8);
#pragma unroll
      for (int i = 0; i < 2; ++i)
        s[i][f] = __builtin_amdgcn_mfma_f32_16x16x32_bf16(qf[i], kf, zf, 0, 0, 0);
    }
    if (kc + 64 <= L) {  // full chunk: scale only (wave-uniform branch)
#pragma unroll
      for (int f = 0; f < 4; ++f)
#pragma unroll
        for (int i = 0; i < 2; ++i)
#pragma unroll
          for (int r = 0; r < 4; ++r) s[i][f][r] *= SCALE;
    } else {             // boundary chunk: mask k only (invalid q rows overwritten by tail)
#pragma unroll
      for (int f = 0; f < 4; ++f) {
        int kr = kc + f * 16 + lrow;
        bool ok = kr < L;
#pragma unroll
        for (int i = 0; i < 2; ++i)
#pragma unroll
          for (int r = 0; r < 4; ++r)
            s[i][f][r] = ok ? s[i][f][r] * SCALE : NEGBIG;
      }
    }
    float alpha[2][4];
#pragma unroll
    for (int i = 0; i < 2; ++i)
#pragma unroll
      for (int r = 0; r < 4; ++r) {
        float mx = fmaxf(fmaxf(s[i][0][r], s[i][1][r]), fmaxf(s[i][2][r], s[i][3][r]));
        mx = fmaxf(mx, __shfl_xor(mx, 1));
        mx = fmaxf(mx, __shfl_xor(mx, 2));
        mx = fmaxf(mx, __shfl_xor(mx, 4));
        mx = fmaxf(mx, __shfl_xor(mx, 8));
        float mnew = fmaxf(m_i[i][r], mx);
        alpha[i][r] = exp2f((m_i[i][r] - mnew) * LOG2E);
        m_i[i][r] = mnew;
        float rs = 0.f;
#pragma unroll
        for (int f = 0; f < 4; ++f) {
          float p = exp2f((s[i][f][r] - mnew) * LOG2E);
          s[i][f][r] = p;
          rs += p;
        }
        rs += __shfl_xor(rs, 1);
        rs += __shfl_xor(rs, 2);
        rs += __shfl_xor(rs, 4);
        rs += __shfl_xor(rs, 8);
        l_i[i][r] = l_i[i][r] * alpha[i][r] + rs;
      }
#pragma unroll
    for (int i = 0; i < 2; ++i)
#pragma unroll
      for (int f = 0; f < 4; ++f)
#pragma unroll
        for (int r = 0; r < 4; ++r)
          P[(i * 16 + lq * 4 + r) * 72 + f * 16 + lrow] = f2bf(s[i][f][r]);
#pragma unroll
    for (int i = 0; i < 2; ++i)
#pragma unroll
      for (int j = 0; j < 2; ++j)
#pragma unroll
        for (int r = 0; r < 4; ++r) o[i][j][r] *= alpha[i][r];
#pragma unroll
    for (int i = 0; i < 2; ++i) {
      bfrag a0 = *(const bfrag*)(P + (i * 16 + lrow) * 72 + lq * 8);
      bfrag a1 = *(const bfrag*)(P + (i * 16 + lrow) * 72 + 32 + lq * 8);
#pragma unroll
      for (int j = 0; j < 2; ++j) {
        bfrag v0 = *(const bfrag*)(Vb + (size_t)(j * 16 + lrow) * 1024 + kc + lq * 8);
        bfrag v1 = *(const bfrag*)(Vb + (size_t)(j * 16 + lrow) * 1024 + kc + 32 + lq * 8);
        o[i][j] = __builtin_amdgcn_mfma_f32_16x16x32_bf16(a0, v0, o[i][j], 0, 0, 0);
        o[i][j] = __builtin_amdgcn_mfma_f32_16x16x32_bf16(a1, v1, o[i][j], 0, 0, 0);
      }
    }
  }

  // ---- tail: invalid q rows get x = (1/1024) * sum_all V  (exact vs reference) ----
  if (nvalid < 32) {
    // reset o, set l=1024 for invalid rows
#pragma unroll
    for (int i = 0; i < 2; ++i)
#pragma unroll
      for (int r = 0; r < 4; ++r) {
        bool inv = (i * 16 + lq * 4 + r) >= nvalid;
        if (inv) {
          l_i[i][r] = 1024.f;
#pragma unroll
          for (int j = 0; j < 2; ++j) o[i][j][r] = 0.f;
        }
      }
    // A-operand indicator frags: lane holds A[m=lrow][k]; all 8 k equal
    bfrag ind[2];
#pragma unroll
    for (int i = 0; i < 2; ++i) {
      short iv = ((i * 16 + lrow) >= nvalid) ? (short)0x3F80 : (short)0;  // bf16 1.0
#pragma unroll
      for (int j = 0; j < 8; ++j) ind[i][j] = iv;
    }
    for (int kc = 0; kc < 1024; kc += 64) {
#pragma unroll
      for (int j = 0; j < 2; ++j) {
        bfrag v0 = *(const bfrag*)(Vb + (size_t)(j * 16 + lrow) * 1024 + kc + lq * 8);
        bfrag v1 = *(const bfrag*)(Vb + (size_t)(j * 16 + lrow) * 1024 + kc + 32 + lq * 8);
#pragma unroll
        for (int i = 0; i < 2; ++i) {
          o[i][j] = __builtin_amdgcn_mfma_f32_16x16x32_bf16(ind[i], v0, o[i][j], 0, 0, 0);
          o[i][j] = __builtin_amdgcn_mfma_f32_16x16x32_bf16(ind[i], v1, o[i][j], 0, 0, 0);
        }
      }
    }
  }

  // write x in place over this head's Q columns
#pragma unroll
  for (int i = 0; i < 2; ++i)
#pragma unroll
    for (int j = 0; j < 2; ++j)
#pragma unroll
      for (int r = 0; r < 4; ++r)
        qx[(i * 16 + lq * 4 + r) * 264 + h * 32 + j * 16 + lrow] =
            f2bf(o[i][j][r] / l_i[i][r]);
  __syncthreads();

  // ---- phase 3: output projection; wave computes cols wid*32..+31 ----
  {
    const int n0 = wid * 32;
    ffrag acc[2][2] = {};
#pragma unroll
    for (int k0 = 0; k0 < 256; k0 += 32) {
      bfrag a[2], b[2];
#pragma unroll
      for (int i = 0; i < 2; ++i)
        a[i] = *(const bfrag*)(qx + (i * 16 + lrow) * 264 + k0 + lq * 8);
#pragma unroll
      for (int j = 0; j < 2; ++j)
        b[j] = cvt8(Wo + (size_t)(n0 + j * 16 + lrow) * 256 + k0 + lq * 8);
#pragma unroll
      for (int i = 0; i < 2; ++i)
#pragma unroll
        for (int j = 0; j < 2; ++j)
          acc[i][j] = __builtin_amdgcn_mfma_f32_16x16x32_bf16(a[i], b[j], acc[i][j], 0, 0, 0);
    }
#pragma unroll
    for (int j = 0; j < 2; ++j) {
      int d = n0 + j * 16 + lrow;
      float bs = bo[d];
#pragma unroll
      for (int i = 0; i < 2; ++i)
#pragma unroll
        for (int r = 0; r < 4; ++r)
          out[((size_t)bt * 1024 + q0 + i * 16 + lq * 4 + r) * 256 + d] =
              acc[i][j][r] + bs;
    }
  }
}

extern "C" void kernel_launch(void* const* d_in, const int* in_sizes, int n_in,
                              void* d_out, int out_size, void* d_ws, size_t ws_size,
                              hipStream_t stream) {
  const float* query = (const float*)d_in[0];
  const float* key   = (const float*)d_in[1];
  const float* value = (const float*)d_in[2];
  const int*   mask  = (const int*)d_in[3];
  const float* Wq = (const float*)d_in[4];
  const float* bq = (const float*)d_in[5];
  const float* Wk = (const float*)d_in[6];
  const float* bk = (const float*)d_in[7];
  const float* Wv = (const float*)d_in[8];
  const float* bv = (const float*)d_in[9];
  const float* Wo = (const float*)d_in[10];
  const float* bo = (const float*)d_in[11];
  float* out = (float*)d_out;

  // workspace: K bf16 (8 MB) + Vt bf16 (8 MB) = 16,777,216 bytes exactly
  short* k_ws  = (short*)d_ws;
  short* vt_ws = k_ws + 4194304;

  proj_k<<<dim3(256, 2), 256, 0, stream>>>(key, Wk, bk, k_ws);
  proj_v<<<dim3(128, 4), 256, 0, stream>>>(value, Wv, bv, vt_ws);
  attn_fused<<<dim3(512), 512, 0, stream>>>(query, Wq, bq, Wo, bo,
                                            k_ws, vt_ws, mask, out);
}